// Round 6
// baseline (160.601 us; speedup 1.0000x reference)
//
#include <hip/hip_runtime.h>
#include <hip/hip_bf16.h>

// Problem constants (B=1)
#define CC   448   // channels
#define CGC  64    // key/query channels
#define MMM  7     // m groups
#define HWSZ 4096  // H*W
#define KK2  49    // K*K
#define GPH  32    // geometry-prior hidden

typedef __attribute__((ext_vector_type(8))) short   short8;   // 8 bf16 (4 VGPRs)
typedef __attribute__((ext_vector_type(4))) float   f32x4;
typedef __attribute__((ext_vector_type(4))) unsigned short us4;

__device__ __forceinline__ unsigned short f2b(float f) {
    union { __hip_bfloat16 h; unsigned short u; } cv;
    cv.h = __float2bfloat16(f);
    return cv.u;
}

// Monotonic grid barrier: never resets -> safe across hipGraph replays and
// rocprof counter replays (zero-init at module load only). All 256 blocks
// are co-resident (154 KB LDS -> 1 block/CU, grid == CU count), so spinning
// is deadlock-free. __threadfence() is an agent-scope fence on gfx950 and
// emits the L2 writeback/invalidate needed across non-coherent XCD L2s.
__device__ unsigned int g_ticket;

__device__ __forceinline__ void grid_sync() {
    __syncthreads();
    if (threadIdx.x == 0) {
        __threadfence();   // release: flush this XCD's L2 to coherent point
        unsigned arrived = __hip_atomic_fetch_add(&g_ticket, 1u,
                               __ATOMIC_ACQ_REL, __HIP_MEMORY_SCOPE_AGENT) + 1u;
        unsigned target = ((arrived + 255u) >> 8) << 8;   // next multiple of 256
        while (__hip_atomic_load(&g_ticket, __ATOMIC_ACQUIRE,
                                 __HIP_MEMORY_SCOPE_AGENT) < target)
            __builtin_amdgcn_s_sleep(2);
        __threadfence();   // acquire: invalidate stale L1/L2 lines
    }
    __syncthreads();
}

#define GLO 196
#define GHI 260
#define PGW (GLO + HWSZ + GHI)   // 4552 words per page
#define NPG 8                    // km + 7 x pages (145664 B)

// One fused kernel, 256 blocks x 1024 threads, 3 phases with 2 grid syncs.
// LDS is a 157696 B union re-viewed per phase (max phase = fconv).
__global__ __launch_bounds__(1024, 4) void fused_all(
    const float* __restrict__ x,
    const float* __restrict__ Wk, const float* __restrict__ bk,
    const float* __restrict__ Wq, const float* __restrict__ bq,
    const float* __restrict__ gw1, const float* __restrict__ gb1,
    const float* __restrict__ gw2, const float* __restrict__ gb2,
    const float* __restrict__ Wf, const float* __restrict__ bfv,
    float* __restrict__ km, float* __restrict__ qm,
    unsigned short* __restrict__ preb,
    float* __restrict__ out)
{
    __shared__ __align__(16) unsigned char smem[157696];

    const int tid  = threadIdx.x;
    const int bid  = blockIdx.x;
    const int lane = tid & 63;
    const int wid  = tid >> 6;
    const int l15  = lane & 15;
    const int l4   = lane >> 4;

    // ================= Phase 1: kq GEMM (verified r5 body) ===============
    // C[128,4096] = [Wk;Wq] @ x, single-shot K=448 staging, split-K waves.
    {
        unsigned short* As  = (unsigned short*)smem;          // [kg56][m128][j8]
        unsigned short* Bs  = As + 57344;                     // [kg56][n16][j8]
        float*          red = (float*)(Bs + 7168);            // 8 x 256

        const int nT = bid * 16;

        #pragma unroll
        for (int i = 0; i < 14; ++i) {
            int idx = tid + i * 1024;
            int row = idx / 112;
            int c   = idx - row * 112;
            const float* src = (row < 64) ? (Wk + (size_t)row * CC)
                                          : (Wq + (size_t)(row - 64) * CC);
            float4 v = *(const float4*)(src + c * 4);
            int kg = c >> 1, jo = (c & 1) * 4;
            *(us4*)&As[kg * 1024 + row * 8 + jo] =
                (us4){ f2b(v.x), f2b(v.y), f2b(v.z), f2b(v.w) };
        }
        #pragma unroll
        for (int i = 0; i < 2; ++i) {
            int idx = tid + i * 1024;
            if (idx < 1792) {
                int row = idx >> 2, c4 = idx & 3;
                float4 v = *(const float4*)(x + (size_t)row * HWSZ + nT + c4 * 4);
                int kg = row >> 3, j = row & 7;
                int b  = kg * 128 + c4 * 32 + j;
                Bs[b]      = f2b(v.x);
                Bs[b + 8]  = f2b(v.y);
                Bs[b + 16] = f2b(v.z);
                Bs[b + 24] = f2b(v.w);
            }
        }
        __syncthreads();

        const int mt = (wid & 7) * 16;
        const int kh = wid >> 3;
        f32x4 acc = (f32x4){0.f, 0.f, 0.f, 0.f};
        #pragma unroll
        for (int i = 0; i < 7; ++i) {
            int K4 = kh * 28 + i * 4;
            short8 fa = *(short8*)&As[(K4 + l4) * 1024 + (mt + l15) * 8];
            short8 fb = *(short8*)&Bs[(K4 + l4) * 128 + l15 * 8];
            acc = __builtin_amdgcn_mfma_f32_16x16x32_bf16(fa, fb, acc, 0, 0, 0);
        }
        if (kh == 1)
            *(f32x4*)&red[(wid & 7) * 256 + lane * 4] = acc;
        __syncthreads();
        if (kh == 0) {
            f32x4 o = *(f32x4*)&red[(wid & 7) * 256 + lane * 4];
            const bool isK = (mt < 64);
            float*       Cd   = isK ? km : qm;
            const float* bias = isK ? bk : bq;
            const int rb = (mt & 63) + l4 * 4;
            #pragma unroll
            for (int r = 0; r < 4; ++r) {
                int row = rb + r;
                Cd[(size_t)row * HWSZ + nT + l15] = acc[r] + o[r] + bias[row];
            }
        }
    }

    grid_sync();

    // ================= Phase 2: attention (verified r5 body, bf16 out) ===
    {
        float* sm    = (float*)smem;                 // NPG pages of PGW words
        float* gpk_s = sm + NPG * PGW;               // 49 words

        const int g  = bid & 63;
        const int lp = (bid >> 6) * 1024 + tid;

        // zero guard bands: 49 + 65 float4 per page, 912 total
        if (tid < NPG * 114) {
            int page = tid / 114;
            int r    = tid - page * 114;
            int w    = (r < 49) ? r * 4 : (GLO + HWSZ + (r - 49) * 4);
            *(float4*)&sm[page * PGW + w] = (float4){0.f, 0.f, 0.f, 0.f};
        }
        // stage payloads: page 0 = km row g, pages 1..7 = x channel m*64+g
        {
            const float4* s0 = (const float4*)(km + (size_t)g * HWSZ);
            *(float4*)&sm[GLO + tid * 4] = s0[tid];
            #pragma unroll
            for (int m = 0; m < MMM; ++m) {
                const float4* sx = (const float4*)(x + (size_t)(m * CGC + g) * HWSZ);
                *(float4*)&sm[(m + 1) * PGW + GLO + tid * 4] = sx[tid];
            }
        }
        // fused geometry prior, row g (49 values)
        if (tid < KK2) {
            int di = tid / 7, dj = tid - di * 7;
            float xp = (float)(dj - 3);
            float yp = (float)(3 - di);
            float a2 = gb2[g];
            #pragma unroll
            for (int j = 0; j < GPH; ++j) {
                float h = fmaxf(gw1[j * 2 + 0] * xp + gw1[j * 2 + 1] * yp + gb1[j], 0.f);
                a2 = fmaf(gw2[g * GPH + j], h, a2);
            }
            gpk_s[tid] = a2;
        }

        // q center tap under the weird view: n = lp*49 + 24
        float qc;
        {
            int nc = lp * KK2 + 24;
            int pc = nc >> 12, lc = nc & 4095;
            int dic = (pc * 37) >> 8, djc = pc - dic * 7;
            int i = (lc >> 6) + dic - 3, j = (lc & 63) + djc - 3;
            bool ok = ((unsigned)i < 64u) && ((unsigned)j < 64u);
            qc = ok ? qm[(size_t)g * HWSZ + i * 64 + j] : 0.f;
        }

        // per-thread segment constants (taps span <=2 p-segments)
        const int n0 = lp * KK2;
        const int p0 = n0 >> 12;
        const int l0 = n0 & 4095;
        const int ts = ((p0 + 1) << 12) - n0;
        const int di0 = (p0 * 37) >> 8, dj0 = p0 - di0 * 7;
        const int p1  = p0 + 1;
        const int di1 = (p1 * 37) >> 8, dj1 = p1 - di1 * 7;
        const int dm0 = dj0 - 3, dm1 = dj1 - 3;
        const int B0 = GLO + l0 + (di0 - 3) * 64 + dm0;
        const int B1 = GLO + l0 - HWSZ + (di1 - 3) * 64 + dm1;
        const int c0 = l0 + (dm0 > 0 ? dm0 : 0), w0 = (dm0 < 0) ? -dm0 : dm0;
        const int c1 = l0 + (dm1 > 0 ? dm1 : 0), w1 = (dm1 < 0) ? -dm1 : dm1;

        __syncthreads();   // everything staged

        float d = 0.f;
        float acc[MMM];
        #pragma unroll
        for (int m = 0; m < MMM; ++m) acc[m] = 0.f;

        #pragma unroll
        for (int tp = 0; tp < 24; ++tp) {
            const int t0 = 2 * tp, t1 = t0 + 1;
            const bool s1 = (t1 >= ts);
            const int bb = s1 ? B1 : B0;
            const int cc = s1 ? c1 : c0;
            const int ww = s1 ? w1 : w0;
            float kv0 = sm[bb + t0];
            float kv1 = sm[bb + t1];
            const bool bad0 = (((cc + t0) & 63) < ww);
            const bool bad1 = (((cc + t1) & 63) < ww);
            kv0 = bad0 ? 0.f : kv0;
            kv1 = bad1 ? 0.f : kv1;
            const float e0 = __expf(fmaf(kv0, qc, gpk_s[t0]));
            const float e1 = __expf(fmaf(kv1, qc, gpk_s[t1]));
            d += e0 + e1;
            const float em0 = bad0 ? 0.f : e0;
            const float em1 = bad1 ? 0.f : e1;
            #pragma unroll
            for (int m = 0; m < MMM; ++m) {
                const int ob = bb + (m + 1) * PGW;
                acc[m] = fmaf(em1, sm[ob + t1], fmaf(em0, sm[ob + t0], acc[m]));
            }
        }
        { // tap 48 singleton
            const bool s1 = (48 >= ts);
            const int bb = s1 ? B1 : B0;
            const int cc = s1 ? c1 : c0;
            const int ww = s1 ? w1 : w0;
            float kv = sm[bb + 48];
            const bool bad = (((cc + 48) & 63) < ww);
            kv = bad ? 0.f : kv;
            const float e = __expf(fmaf(kv, qc, gpk_s[48]));
            d += e;
            const float em = bad ? 0.f : e;
            #pragma unroll
            for (int m = 0; m < MMM; ++m)
                acc[m] = fmaf(em, sm[bb + (m + 1) * PGW + 48], acc[m]);
        }
        // fixup: odd ts < 49 -> tap ts-1 used seg1 base; swap for seg0.
        if (ts < 49 && (ts & 1)) {
            const int tw = ts - 1;
            const float gw = gpk_s[tw];
            float kw = sm[B1 + tw];
            const bool bw = (((c1 + tw) & 63) < w1);
            kw = bw ? 0.f : kw;
            const float ew  = __expf(fmaf(kw, qc, gw));
            const float emw = bw ? 0.f : ew;
            float kr = sm[B0 + tw];
            const bool br = (((c0 + tw) & 63) < w0);
            kr = br ? 0.f : kr;
            const float er  = __expf(fmaf(kr, qc, gw));
            const float emr = br ? 0.f : er;
            d += er - ew;
            #pragma unroll
            for (int m = 0; m < MMM; ++m)
                acc[m] += emr * sm[B0 + (m + 1) * PGW + tw]
                        - emw * sm[B1 + (m + 1) * PGW + tw];
        }

        const float inv = 1.f / d;
        #pragma unroll
        for (int m = 0; m < MMM; ++m)
            preb[(size_t)(m * CGC + g) * HWSZ + lp] = f2b(acc[m] * inv);
    }

    grid_sync();

    // ================= Phase 3: fconv GEMM (r5 body, bf16 B input) =======
    {
        unsigned short* As = (unsigned short*)smem;   // [kg56][m112][j8]
        unsigned short* Bs = As + 50176;              // [kg56][n64][j8]

        const int nT = (bid >> 2) * 64;
        const int oT = (bid & 3) * 112;

        #pragma unroll
        for (int i = 0; i < 13; ++i) {
            int idx = tid + i * 1024;
            if (idx < 12544) {
                int row = idx / 112;
                int c   = idx - row * 112;
                float4 v = *(const float4*)(Wf + (size_t)(oT + row) * CC + c * 4);
                int kg = c >> 1, jo = (c & 1) * 4;
                *(us4*)&As[kg * 896 + row * 8 + jo] =
                    (us4){ f2b(v.x), f2b(v.y), f2b(v.z), f2b(v.w) };
            }
        }
        #pragma unroll
        for (int i = 0; i < 7; ++i) {
            int idx = tid + i * 1024;
            int row = idx >> 4, c4 = idx & 15;
            us4 v = *(const us4*)(preb + (size_t)row * HWSZ + nT + c4 * 4);
            int kg = row >> 3, j = row & 7;
            int b  = kg * 512 + c4 * 32 + j;
            Bs[b]      = v.x;
            Bs[b + 8]  = v.y;
            Bs[b + 16] = v.z;
            Bs[b + 24] = v.w;
        }
        __syncthreads();

        if (wid < 14) {
            const int mt = (wid % 7) * 16;
            const int np = wid / 7;
            f32x4 a0 = (f32x4){0.f, 0.f, 0.f, 0.f};
            f32x4 a1 = (f32x4){0.f, 0.f, 0.f, 0.f};
            #pragma unroll
            for (int i = 0; i < 14; ++i) {
                int K4 = i * 4;
                short8 fa  = *(short8*)&As[(K4 + l4) * 896 + (mt + l15) * 8];
                short8 fb0 = *(short8*)&Bs[(K4 + l4) * 512 + (np * 32 + l15) * 8];
                short8 fb1 = *(short8*)&Bs[(K4 + l4) * 512 + (np * 32 + 16 + l15) * 8];
                a0 = __builtin_amdgcn_mfma_f32_16x16x32_bf16(fa, fb0, a0, 0, 0, 0);
                a1 = __builtin_amdgcn_mfma_f32_16x16x32_bf16(fa, fb1, a1, 0, 0, 0);
            }
            #pragma unroll
            for (int wn2 = 0; wn2 < 2; ++wn2) {
                const f32x4 a = wn2 ? a1 : a0;
                #pragma unroll
                for (int r = 0; r < 4; ++r) {
                    int row = oT + mt + l4 * 4 + r;
                    int col = nT + np * 32 + wn2 * 16 + l15;
                    out[(size_t)row * HWSZ + col] = a[r] + bfv[row];
                }
            }
        }
    }
}

extern "C" void kernel_launch(void* const* d_in, const int* in_sizes, int n_in,
                              void* d_out, int out_size, void* d_ws, size_t ws_size,
                              hipStream_t stream) {
    const float* x   = (const float*)d_in[0];
    const float* Wk  = (const float*)d_in[1];
    const float* bk  = (const float*)d_in[2];
    const float* Wq  = (const float*)d_in[3];
    const float* bq  = (const float*)d_in[4];
    const float* gw1 = (const float*)d_in[5];
    const float* gb1 = (const float*)d_in[6];
    const float* gw2 = (const float*)d_in[7];
    const float* gb2 = (const float*)d_in[8];
    const float* Wf  = (const float*)d_in[9];
    const float* bfv = (const float*)d_in[10];
    float* out = (float*)d_out;

    float* km  = (float*)d_ws;                              // 64*4096 f32
    float* qm  = km + CGC * HWSZ;                           // 64*4096 f32
    unsigned short* preb = (unsigned short*)(qm + CGC * HWSZ);  // 448*4096 bf16

    fused_all<<<dim3(256), 1024, 0, stream>>>(
        x, Wk, bk, Wq, bq, gw1, gb1, gw2, gb2, Wf, bfv, km, qm, preb, out);
}

// Round 7
// 108.831 us; speedup vs baseline: 1.4757x; 1.4757x over previous
//
#include <hip/hip_runtime.h>
#include <hip/hip_bf16.h>

// Problem constants (B=1)
#define CC   448   // channels
#define CGC  64    // key/query channels
#define MMM  7     // m groups
#define HWSZ 4096  // H*W
#define KK2  49    // K*K
#define GPH  32    // geometry-prior hidden

typedef __attribute__((ext_vector_type(8))) short   short8;   // 8 bf16 (4 VGPRs)
typedef __attribute__((ext_vector_type(4))) float   f32x4;
typedef __attribute__((ext_vector_type(4))) unsigned short us4;

__device__ __forceinline__ unsigned short f2b(float f) {
    union { __hip_bfloat16 h; unsigned short u; } cv;
    cv.h = __float2bfloat16(f);
    return cv.u;
}

// Padded kg-strides: word-stride == 4 (mod 32) -> staging writes ~4-way
// (was 32-way at stride 1024/896: kg*2048B == bank 0 for all kg). All
// strides are multiples of 8 shorts (16 B) so ds_read_b128 stays aligned.
#define KQ_AS  1032   // kq A kg-stride (shorts)
#define KQ_BS  136    // kq B kg-stride
#define FC_AS  904    // fconv A kg-stride
#define FC_BS  520    // fconv B kg-stride

// ---------------- Kernel 1: fused k+q GEMM, single-shot staging ----------
// C[128,4096] = [Wk;Wq] @ x, 256 blocks x 1024 thr. All of K=448 staged in
// LDS at once: 1 load burst, 1 barrier, 7 MFMAs/wave split-K, reduce, store.
__global__ __launch_bounds__(1024, 4) void kq_mfma(
    const float* __restrict__ x,
    const float* __restrict__ Wk, const float* __restrict__ bk,
    const float* __restrict__ Wq, const float* __restrict__ bq,
    float* __restrict__ km, float* __restrict__ qm)
{
    __shared__ unsigned short As[56 * KQ_AS];  // 115584 B
    __shared__ unsigned short Bs[56 * KQ_BS];  //  15232 B
    __shared__ float         red[2048];        //   8192 B  (total 139008)

    const int tid  = threadIdx.x;
    const int nT   = blockIdx.x * 16;
    const int lane = tid & 63;
    const int wid  = tid >> 6;
    const int l15  = lane & 15;
    const int l4   = lane >> 4;

    // stage A: 128 rows x 112 float4 = 14336 f4, 14/thread, coalesced
    #pragma unroll
    for (int i = 0; i < 14; ++i) {
        int idx = tid + i * 1024;
        int row = idx / 112;              // 0..127
        int c   = idx - row * 112;        // f4 within row
        const float* src = (row < 64) ? (Wk + (size_t)row * CC)
                                      : (Wq + (size_t)(row - 64) * CC);
        float4 v = *(const float4*)(src + c * 4);
        int kg = c >> 1, jo = (c & 1) * 4;
        *(us4*)&As[kg * KQ_AS + row * 8 + jo] =
            (us4){ f2b(v.x), f2b(v.y), f2b(v.z), f2b(v.w) };
    }
    // stage B: 448 rows x 4 float4 = 1792 f4
    #pragma unroll
    for (int i = 0; i < 2; ++i) {
        int idx = tid + i * 1024;
        if (idx < 1792) {
            int row = idx >> 2, c4 = idx & 3;
            float4 v = *(const float4*)(x + (size_t)row * HWSZ + nT + c4 * 4);
            int kg = row >> 3, j = row & 7;
            int b  = kg * KQ_BS + c4 * 32 + j;
            Bs[b]      = f2b(v.x);
            Bs[b + 8]  = f2b(v.y);
            Bs[b + 16] = f2b(v.z);
            Bs[b + 24] = f2b(v.w);
        }
    }
    __syncthreads();

    // wave w: m-tile (w&7)*16, K-half (w>>3)*224
    const int mt = (wid & 7) * 16;
    const int kh = wid >> 3;
    f32x4 acc = (f32x4){0.f, 0.f, 0.f, 0.f};
    #pragma unroll
    for (int i = 0; i < 7; ++i) {
        int K4 = kh * 28 + i * 4;
        short8 fa = *(short8*)&As[(K4 + l4) * KQ_AS + (mt + l15) * 8];
        short8 fb = *(short8*)&Bs[(K4 + l4) * KQ_BS + l15 * 8];
        acc = __builtin_amdgcn_mfma_f32_16x16x32_bf16(fa, fb, acc, 0, 0, 0);
    }
    if (kh == 1)
        *(f32x4*)&red[(wid & 7) * 256 + lane * 4] = acc;
    __syncthreads();
    if (kh == 0) {
        f32x4 o = *(f32x4*)&red[(wid & 7) * 256 + lane * 4];
        const bool isK = (mt < 64);
        float*       Cd   = isK ? km : qm;
        const float* bias = isK ? bk : bq;
        const int rb = (mt & 63) + l4 * 4;
        #pragma unroll
        for (int r = 0; r < 4; ++r) {
            int row = rb + r;
            Cd[(size_t)row * HWSZ + nT + l15] = acc[r] + o[r] + bias[row];
        }
    }
}

// ---------------- Kernel 3: fconv GEMM, single-shot staging, bf16 B ------
// out[448,4096] = Wf @ preb. 256 blocks x 1024 thr: (4 row-tiles of 112) x
// (64 col-tiles of 64). 1 barrier, 14 waves x 28 MFMAs. LDS 159488 B.
__global__ __launch_bounds__(1024, 4) void fconv_mfma(
    const unsigned short* __restrict__ preb,
    const float* __restrict__ Wf, const float* __restrict__ bfv,
    float* __restrict__ out)
{
    __shared__ unsigned short As[56 * FC_AS];  // 101248 B
    __shared__ unsigned short Bs[56 * FC_BS];  //  58240 B

    const int tid  = threadIdx.x;
    const int bid  = blockIdx.x;          // 0..255
    const int nT   = (bid >> 2) * 64;
    const int oT   = (bid & 3) * 112;
    const int lane = tid & 63;
    const int wid  = tid >> 6;
    const int l15  = lane & 15;
    const int l4   = lane >> 4;

    // stage A: 112 rows x 112 f4 = 12544 f4
    #pragma unroll
    for (int i = 0; i < 13; ++i) {
        int idx = tid + i * 1024;
        if (idx < 12544) {
            int row = idx / 112;
            int c   = idx - row * 112;
            float4 v = *(const float4*)(Wf + (size_t)(oT + row) * CC + c * 4);
            int kg = c >> 1, jo = (c & 1) * 4;
            *(us4*)&As[kg * FC_AS + row * 8 + jo] =
                (us4){ f2b(v.x), f2b(v.y), f2b(v.z), f2b(v.w) };
        }
    }
    // stage B (bf16 source): 448 rows x 16 us4 = 7168 (exactly 7/thread)
    #pragma unroll
    for (int i = 0; i < 7; ++i) {
        int idx = tid + i * 1024;
        int row = idx >> 4, c4 = idx & 15;
        us4 v = *(const us4*)(preb + (size_t)row * HWSZ + nT + c4 * 4);
        int kg = row >> 3, j = row & 7;
        int b  = kg * FC_BS + c4 * 32 + j;
        Bs[b]      = v.x;
        Bs[b + 8]  = v.y;
        Bs[b + 16] = v.z;
        Bs[b + 24] = v.w;
    }
    __syncthreads();

    if (wid < 14) {
        const int mt = (wid % 7) * 16;
        const int np = wid / 7;           // n-pair: covers n-tiles {2np, 2np+1}
        f32x4 a0 = (f32x4){0.f, 0.f, 0.f, 0.f};
        f32x4 a1 = (f32x4){0.f, 0.f, 0.f, 0.f};
        #pragma unroll
        for (int i = 0; i < 14; ++i) {
            int K4 = i * 4;
            short8 fa  = *(short8*)&As[(K4 + l4) * FC_AS + (mt + l15) * 8];
            short8 fb0 = *(short8*)&Bs[(K4 + l4) * FC_BS + (np * 32 + l15) * 8];
            short8 fb1 = *(short8*)&Bs[(K4 + l4) * FC_BS + (np * 32 + 16 + l15) * 8];
            a0 = __builtin_amdgcn_mfma_f32_16x16x32_bf16(fa, fb0, a0, 0, 0, 0);
            a1 = __builtin_amdgcn_mfma_f32_16x16x32_bf16(fa, fb1, a1, 0, 0, 0);
        }
        #pragma unroll
        for (int wn2 = 0; wn2 < 2; ++wn2) {
            const f32x4 a = wn2 ? a1 : a0;
            #pragma unroll
            for (int r = 0; r < 4; ++r) {
                int row = oT + mt + l4 * 4 + r;
                int col = nT + np * 32 + wn2 * 16 + l15;
                out[(size_t)row * HWSZ + col] = a[r] + bfv[row];
            }
        }
    }
}

// ---------------- Kernel 2: attention (r5 verified body, bf16 out) -------
#define GLO 196
#define GHI 260
#define PGW (GLO + HWSZ + GHI)   // 4552 words per page
#define NPG 8                    // km + 7 x pages (145664 B)

__global__ __launch_bounds__(1024, 4) void attn_kernel(
    const float* __restrict__ km, const float* __restrict__ qm,
    const float* __restrict__ x,
    const float* __restrict__ gw1, const float* __restrict__ gb1,
    const float* __restrict__ gw2, const float* __restrict__ gb2,
    unsigned short* __restrict__ preb)
{
    __shared__ __align__(16) float sm[NPG * PGW];
    __shared__ float gpk_s[KK2];

    const int tid = threadIdx.x;
    const int g   = blockIdx.y;
    const int lp  = blockIdx.x * 1024 + tid;

    // zero guard bands: 49 + 65 float4 per page, 912 total
    if (tid < NPG * 114) {
        int page = tid / 114;
        int r    = tid - page * 114;
        int w    = (r < 49) ? r * 4 : (GLO + HWSZ + (r - 49) * 4);
        *(float4*)&sm[page * PGW + w] = (float4){0.f, 0.f, 0.f, 0.f};
    }
    // stage payloads: page 0 = km row g, pages 1..7 = x channel m*64+g
    {
        const float4* s0 = (const float4*)(km + (size_t)g * HWSZ);
        *(float4*)&sm[GLO + tid * 4] = s0[tid];
        #pragma unroll
        for (int m = 0; m < MMM; ++m) {
            const float4* sx = (const float4*)(x + (size_t)(m * CGC + g) * HWSZ);
            *(float4*)&sm[(m + 1) * PGW + GLO + tid * 4] = sx[tid];
        }
    }
    // fused geometry prior, row g (49 values)
    if (tid < KK2) {
        int di = tid / 7, dj = tid - di * 7;
        float xp = (float)(dj - 3);
        float yp = (float)(3 - di);
        float a2 = gb2[g];
        #pragma unroll
        for (int j = 0; j < GPH; ++j) {
            float h = fmaxf(gw1[j * 2 + 0] * xp + gw1[j * 2 + 1] * yp + gb1[j], 0.f);
            a2 = fmaf(gw2[g * GPH + j], h, a2);
        }
        gpk_s[tid] = a2;
    }

    // q center tap under the weird view: n = lp*49 + 24
    float qc;
    {
        int nc = lp * KK2 + 24;
        int pc = nc >> 12, lc = nc & 4095;
        int dic = (pc * 37) >> 8, djc = pc - dic * 7;
        int i = (lc >> 6) + dic - 3, j = (lc & 63) + djc - 3;
        bool ok = ((unsigned)i < 64u) && ((unsigned)j < 64u);
        qc = ok ? qm[(size_t)g * HWSZ + i * 64 + j] : 0.f;
    }

    // per-thread segment constants (taps span <=2 p-segments)
    const int n0 = lp * KK2;
    const int p0 = n0 >> 12;
    const int l0 = n0 & 4095;
    const int ts = ((p0 + 1) << 12) - n0;          // taps in segment 0 (>=1)
    const int di0 = (p0 * 37) >> 8, dj0 = p0 - di0 * 7;
    const int p1  = p0 + 1;
    const int di1 = (p1 * 37) >> 8, dj1 = p1 - di1 * 7;
    const int dm0 = dj0 - 3, dm1 = dj1 - 3;
    const int B0 = GLO + l0 + (di0 - 3) * 64 + dm0;
    const int B1 = GLO + l0 - HWSZ + (di1 - 3) * 64 + dm1;
    // unified j-mask: bad <=> ((c + t) & 63) < w
    const int c0 = l0 + (dm0 > 0 ? dm0 : 0), w0 = (dm0 < 0) ? -dm0 : dm0;
    const int c1 = l0 + (dm1 > 0 ? dm1 : 0), w1 = (dm1 < 0) ? -dm1 : dm1;

    __syncthreads();   // everything staged; only barrier in the kernel

    float d = 0.f;
    float acc[MMM];
    #pragma unroll
    for (int m = 0; m < MMM; ++m) acc[m] = 0.f;

    // 24 tap-pairs, one base/mask select per pair
    #pragma unroll
    for (int tp = 0; tp < 24; ++tp) {
        const int t0 = 2 * tp, t1 = t0 + 1;
        const bool s1 = (t1 >= ts);
        const int bb = s1 ? B1 : B0;
        const int cc = s1 ? c1 : c0;
        const int ww = s1 ? w1 : w0;
        float kv0 = sm[bb + t0];
        float kv1 = sm[bb + t1];
        const bool bad0 = (((cc + t0) & 63) < ww);
        const bool bad1 = (((cc + t1) & 63) < ww);
        kv0 = bad0 ? 0.f : kv0;
        kv1 = bad1 ? 0.f : kv1;
        const float e0 = __expf(fmaf(kv0, qc, gpk_s[t0]));
        const float e1 = __expf(fmaf(kv1, qc, gpk_s[t1]));
        d += e0 + e1;
        const float em0 = bad0 ? 0.f : e0;
        const float em1 = bad1 ? 0.f : e1;
        #pragma unroll
        for (int m = 0; m < MMM; ++m) {
            const int ob = bb + (m + 1) * PGW;
            acc[m] = fmaf(em1, sm[ob + t1], fmaf(em0, sm[ob + t0], acc[m]));
        }
    }
    { // tap 48 singleton
        const bool s1 = (48 >= ts);
        const int bb = s1 ? B1 : B0;
        const int cc = s1 ? c1 : c0;
        const int ww = s1 ? w1 : w0;
        float kv = sm[bb + 48];
        const bool bad = (((cc + 48) & 63) < ww);
        kv = bad ? 0.f : kv;
        const float e = __expf(fmaf(kv, qc, gpk_s[48]));
        d += e;
        const float em = bad ? 0.f : e;
        #pragma unroll
        for (int m = 0; m < MMM; ++m)
            acc[m] = fmaf(em, sm[bb + (m + 1) * PGW + 48], acc[m]);
    }
    // fixup: odd ts < 49 -> tap ts-1 used seg1 base; swap for seg0.
    if (ts < 49 && (ts & 1)) {
        const int tw = ts - 1;
        const float gw = gpk_s[tw];
        float kw = sm[B1 + tw];
        const bool bw = (((c1 + tw) & 63) < w1);
        kw = bw ? 0.f : kw;
        const float ew  = __expf(fmaf(kw, qc, gw));
        const float emw = bw ? 0.f : ew;
        float kr = sm[B0 + tw];
        const bool br = (((c0 + tw) & 63) < w0);
        kr = br ? 0.f : kr;
        const float er  = __expf(fmaf(kr, qc, gw));
        const float emr = br ? 0.f : er;
        d += er - ew;
        #pragma unroll
        for (int m = 0; m < MMM; ++m)
            acc[m] += emr * sm[B0 + (m + 1) * PGW + tw]
                    - emw * sm[B1 + (m + 1) * PGW + tw];
    }

    const float inv = 1.f / d;
    #pragma unroll
    for (int m = 0; m < MMM; ++m)
        preb[(size_t)(m * CGC + g) * HWSZ + lp] = f2b(acc[m] * inv);
}

extern "C" void kernel_launch(void* const* d_in, const int* in_sizes, int n_in,
                              void* d_out, int out_size, void* d_ws, size_t ws_size,
                              hipStream_t stream) {
    const float* x   = (const float*)d_in[0];
    const float* Wk  = (const float*)d_in[1];
    const float* bk  = (const float*)d_in[2];
    const float* Wq  = (const float*)d_in[3];
    const float* bq  = (const float*)d_in[4];
    const float* gw1 = (const float*)d_in[5];
    const float* gb1 = (const float*)d_in[6];
    const float* gw2 = (const float*)d_in[7];
    const float* gb2 = (const float*)d_in[8];
    const float* Wf  = (const float*)d_in[9];
    const float* bfv = (const float*)d_in[10];
    float* out = (float*)d_out;

    float* km  = (float*)d_ws;                              // 64*4096 f32
    float* qm  = km + CGC * HWSZ;                           // 64*4096 f32
    unsigned short* preb = (unsigned short*)(qm + CGC * HWSZ);  // 448*4096 bf16

    kq_mfma    <<<dim3(256),    1024, 0, stream>>>(x, Wk, bk, Wq, bq, km, qm);
    attn_kernel<<<dim3(4, CGC), 1024, 0, stream>>>(km, qm, x, gw1, gb1, gw2, gb2, preb);
    fconv_mfma <<<dim3(256),    1024, 0, stream>>>(preb, Wf, bfv, out);
}

// Round 8
// 107.504 us; speedup vs baseline: 1.4939x; 1.0123x over previous
//
#include <hip/hip_runtime.h>
#include <hip/hip_bf16.h>

// Problem constants (B=1)
#define CC   448   // channels
#define CGC  64    // key/query channels
#define MMM  7     // m groups
#define HWSZ 4096  // H*W
#define KK2  49    // K*K
#define GPH  32    // geometry-prior hidden

typedef __attribute__((ext_vector_type(8))) short   short8;   // 8 bf16 (4 VGPRs)
typedef __attribute__((ext_vector_type(4))) float   f32x4;
typedef __attribute__((ext_vector_type(4))) unsigned short us4;

__device__ __forceinline__ unsigned short f2b(float f) {
    union { __hip_bfloat16 h; unsigned short u; } cv;
    cv.h = __float2bfloat16(f);
    return cv.u;
}

// Padded kg-strides (stride == 4 mod 32, 16B-aligned) from r7.
#define KQ_AS  1032   // kq A kg-stride (shorts)
#define KQ_BS  136    // kq B kg-stride
#define FC_AS  904    // fconv A kg-stride
#define FC_BS  520    // fconv B kg-stride

// ---------------- Kernel 1: fused k+q GEMM, single-shot staging ----------
__global__ __launch_bounds__(1024, 4) void kq_mfma(
    const float* __restrict__ x,
    const float* __restrict__ Wk, const float* __restrict__ bk,
    const float* __restrict__ Wq, const float* __restrict__ bq,
    float* __restrict__ km, float* __restrict__ qm)
{
    __shared__ unsigned short As[56 * KQ_AS];  // 115584 B
    __shared__ unsigned short Bs[56 * KQ_BS];  //  15232 B
    __shared__ float         red[2048];        //   8192 B

    const int tid  = threadIdx.x;
    const int nT   = blockIdx.x * 16;
    const int lane = tid & 63;
    const int wid  = tid >> 6;
    const int l15  = lane & 15;
    const int l4   = lane >> 4;

    #pragma unroll
    for (int i = 0; i < 14; ++i) {
        int idx = tid + i * 1024;
        int row = idx / 112;
        int c   = idx - row * 112;
        const float* src = (row < 64) ? (Wk + (size_t)row * CC)
                                      : (Wq + (size_t)(row - 64) * CC);
        float4 v = *(const float4*)(src + c * 4);
        int kg = c >> 1, jo = (c & 1) * 4;
        *(us4*)&As[kg * KQ_AS + row * 8 + jo] =
            (us4){ f2b(v.x), f2b(v.y), f2b(v.z), f2b(v.w) };
    }
    #pragma unroll
    for (int i = 0; i < 2; ++i) {
        int idx = tid + i * 1024;
        if (idx < 1792) {
            int row = idx >> 2, c4 = idx & 3;
            float4 v = *(const float4*)(x + (size_t)row * HWSZ + nT + c4 * 4);
            int kg = row >> 3, j = row & 7;
            int b  = kg * KQ_BS + c4 * 32 + j;
            Bs[b]      = f2b(v.x);
            Bs[b + 8]  = f2b(v.y);
            Bs[b + 16] = f2b(v.z);
            Bs[b + 24] = f2b(v.w);
        }
    }
    __syncthreads();

    const int mt = (wid & 7) * 16;
    const int kh = wid >> 3;
    f32x4 acc = (f32x4){0.f, 0.f, 0.f, 0.f};
    #pragma unroll
    for (int i = 0; i < 7; ++i) {
        int K4 = kh * 28 + i * 4;
        short8 fa = *(short8*)&As[(K4 + l4) * KQ_AS + (mt + l15) * 8];
        short8 fb = *(short8*)&Bs[(K4 + l4) * KQ_BS + l15 * 8];
        acc = __builtin_amdgcn_mfma_f32_16x16x32_bf16(fa, fb, acc, 0, 0, 0);
    }
    if (kh == 1)
        *(f32x4*)&red[(wid & 7) * 256 + lane * 4] = acc;
    __syncthreads();
    if (kh == 0) {
        f32x4 o = *(f32x4*)&red[(wid & 7) * 256 + lane * 4];
        const bool isK = (mt < 64);
        float*       Cd   = isK ? km : qm;
        const float* bias = isK ? bk : bq;
        const int rb = (mt & 63) + l4 * 4;
        #pragma unroll
        for (int r = 0; r < 4; ++r) {
            int row = rb + r;
            Cd[(size_t)row * HWSZ + nT + l15] = acc[r] + o[r] + bias[row];
        }
    }
}

// ---------------- Kernel 3: fconv GEMM, single-shot staging, bf16 B ------
__global__ __launch_bounds__(1024, 4) void fconv_mfma(
    const unsigned short* __restrict__ preb,
    const float* __restrict__ Wf, const float* __restrict__ bfv,
    float* __restrict__ out)
{
    __shared__ unsigned short As[56 * FC_AS];  // 101248 B
    __shared__ unsigned short Bs[56 * FC_BS];  //  58240 B

    const int tid  = threadIdx.x;
    const int bid  = blockIdx.x;          // 0..255
    const int nT   = (bid >> 2) * 64;
    const int oT   = (bid & 3) * 112;
    const int lane = tid & 63;
    const int wid  = tid >> 6;
    const int l15  = lane & 15;
    const int l4   = lane >> 4;

    #pragma unroll
    for (int i = 0; i < 13; ++i) {
        int idx = tid + i * 1024;
        if (idx < 12544) {
            int row = idx / 112;
            int c   = idx - row * 112;
            float4 v = *(const float4*)(Wf + (size_t)(oT + row) * CC + c * 4);
            int kg = c >> 1, jo = (c & 1) * 4;
            *(us4*)&As[kg * FC_AS + row * 8 + jo] =
                (us4){ f2b(v.x), f2b(v.y), f2b(v.z), f2b(v.w) };
        }
    }
    #pragma unroll
    for (int i = 0; i < 7; ++i) {
        int idx = tid + i * 1024;
        int row = idx >> 4, c4 = idx & 15;
        us4 v = *(const us4*)(preb + (size_t)row * HWSZ + nT + c4 * 4);
        int kg = row >> 3, j = row & 7;
        int b  = kg * FC_BS + c4 * 32 + j;
        Bs[b]      = v.x;
        Bs[b + 8]  = v.y;
        Bs[b + 16] = v.z;
        Bs[b + 24] = v.w;
    }
    __syncthreads();

    if (wid < 14) {
        const int mt = (wid % 7) * 16;
        const int np = wid / 7;
        f32x4 a0 = (f32x4){0.f, 0.f, 0.f, 0.f};
        f32x4 a1 = (f32x4){0.f, 0.f, 0.f, 0.f};
        #pragma unroll
        for (int i = 0; i < 14; ++i) {
            int K4 = i * 4;
            short8 fa  = *(short8*)&As[(K4 + l4) * FC_AS + (mt + l15) * 8];
            short8 fb0 = *(short8*)&Bs[(K4 + l4) * FC_BS + (np * 32 + l15) * 8];
            short8 fb1 = *(short8*)&Bs[(K4 + l4) * FC_BS + (np * 32 + 16 + l15) * 8];
            a0 = __builtin_amdgcn_mfma_f32_16x16x32_bf16(fa, fb0, a0, 0, 0, 0);
            a1 = __builtin_amdgcn_mfma_f32_16x16x32_bf16(fa, fb1, a1, 0, 0, 0);
        }
        #pragma unroll
        for (int wn2 = 0; wn2 < 2; ++wn2) {
            const f32x4 a = wn2 ? a1 : a0;
            #pragma unroll
            for (int r = 0; r < 4; ++r) {
                int row = oT + mt + l4 * 4 + r;
                int col = nT + np * 32 + wn2 * 16 + l15;
                out[(size_t)row * HWSZ + col] = a[r] + bfv[row];
            }
        }
    }
}

// ---------------- Kernel 2: attention, bf16x2-packed x pages -------------
// Same verified weird-view indexing as r5/r7. km page stays f32; the 7
// x-channels are packed as bf16 pairs (m,m+1) into 4 u32 pages -> per
// tap-pair: 1 kv read2 + 4 packed read2 = 5 LDS ops (was 8). Unpack is
// 1-2 VALU per word (<<16 / &0xffff0000). LDS 91 KB (was 145).
#define GLO 196
#define GHI 260
#define PGW (GLO + HWSZ + GHI)   // 4552 words per page

__global__ __launch_bounds__(1024, 4) void attn_kernel(
    const float* __restrict__ km, const float* __restrict__ qm,
    const float* __restrict__ x,
    const float* __restrict__ gw1, const float* __restrict__ gb1,
    const float* __restrict__ gw2, const float* __restrict__ gb2,
    unsigned short* __restrict__ preb)
{
    __shared__ __align__(16) float        smk[PGW];        // km page (f32)
    __shared__ __align__(16) unsigned int smx[4 * PGW];    // packed x pages
    __shared__ float gpk_s[KK2];

    const int tid = threadIdx.x;
    const int g   = blockIdx.y;
    const int lp  = blockIdx.x * 1024 + tid;

    // zero guard bands: 5 pages x (49 lo + 65 hi) float4 regions
    if (tid < 5 * 114) {
        int page = tid / 114;
        int r    = tid - page * 114;
        int w    = (r < 49) ? r * 4 : (GLO + HWSZ + (r - 49) * 4);
        if (page == 0)
            *(float4*)&smk[w] = (float4){0.f, 0.f, 0.f, 0.f};
        else
            *(uint4*)&smx[(page - 1) * PGW + w] = (uint4){0u, 0u, 0u, 0u};
    }
    // stage km page (f32)
    {
        const float4* s0 = (const float4*)(km + (size_t)g * HWSZ);
        *(float4*)&smk[GLO + tid * 4] = s0[tid];
    }
    // stage packed x pages: pp holds (m=2pp low, m=2pp+1 high); pp=3 high=0
    #pragma unroll
    for (int pp = 0; pp < 4; ++pp) {
        const float4* xa = (const float4*)(x + (size_t)(2 * pp * CGC + g) * HWSZ);
        float4 a = xa[tid];
        float4 b = (float4){0.f, 0.f, 0.f, 0.f};
        if (pp < 3) {
            const float4* xb = (const float4*)(x + (size_t)((2 * pp + 1) * CGC + g) * HWSZ);
            b = xb[tid];
        }
        uint4 w;
        w.x = ((unsigned)f2b(b.x) << 16) | f2b(a.x);
        w.y = ((unsigned)f2b(b.y) << 16) | f2b(a.y);
        w.z = ((unsigned)f2b(b.z) << 16) | f2b(a.z);
        w.w = ((unsigned)f2b(b.w) << 16) | f2b(a.w);
        *(uint4*)&smx[pp * PGW + GLO + tid * 4] = w;
    }
    // fused geometry prior, row g (49 values)
    if (tid < KK2) {
        int di = tid / 7, dj = tid - di * 7;
        float xp = (float)(dj - 3);
        float yp = (float)(3 - di);
        float a2 = gb2[g];
        #pragma unroll
        for (int j = 0; j < GPH; ++j) {
            float h = fmaxf(gw1[j * 2 + 0] * xp + gw1[j * 2 + 1] * yp + gb1[j], 0.f);
            a2 = fmaf(gw2[g * GPH + j], h, a2);
        }
        gpk_s[tid] = a2;
    }

    // q center tap under the weird view: n = lp*49 + 24
    float qc;
    {
        int nc = lp * KK2 + 24;
        int pc = nc >> 12, lc = nc & 4095;
        int dic = (pc * 37) >> 8, djc = pc - dic * 7;
        int i = (lc >> 6) + dic - 3, j = (lc & 63) + djc - 3;
        bool ok = ((unsigned)i < 64u) && ((unsigned)j < 64u);
        qc = ok ? qm[(size_t)g * HWSZ + i * 64 + j] : 0.f;
    }

    // per-thread segment constants (taps span <=2 p-segments)
    const int n0 = lp * KK2;
    const int p0 = n0 >> 12;
    const int l0 = n0 & 4095;
    const int ts = ((p0 + 1) << 12) - n0;          // taps in segment 0 (>=1)
    const int di0 = (p0 * 37) >> 8, dj0 = p0 - di0 * 7;
    const int p1  = p0 + 1;
    const int di1 = (p1 * 37) >> 8, dj1 = p1 - di1 * 7;
    const int dm0 = dj0 - 3, dm1 = dj1 - 3;
    const int B0 = GLO + l0 + (di0 - 3) * 64 + dm0;
    const int B1 = GLO + l0 - HWSZ + (di1 - 3) * 64 + dm1;
    const int c0 = l0 + (dm0 > 0 ? dm0 : 0), w0 = (dm0 < 0) ? -dm0 : dm0;
    const int c1 = l0 + (dm1 > 0 ? dm1 : 0), w1 = (dm1 < 0) ? -dm1 : dm1;

    __syncthreads();   // everything staged; only barrier in the kernel

    float d = 0.f;
    float acc[MMM];
    #pragma unroll
    for (int m = 0; m < MMM; ++m) acc[m] = 0.f;

    // 24 tap-pairs, one base/mask select per pair; packed x reads
    #pragma unroll
    for (int tp = 0; tp < 24; ++tp) {
        const int t0 = 2 * tp, t1 = t0 + 1;
        const bool s1 = (t1 >= ts);
        const int bb = s1 ? B1 : B0;
        const int cc = s1 ? c1 : c0;
        const int ww = s1 ? w1 : w0;
        float kv0 = smk[bb + t0];
        float kv1 = smk[bb + t1];
        const bool bad0 = (((cc + t0) & 63) < ww);
        const bool bad1 = (((cc + t1) & 63) < ww);
        kv0 = bad0 ? 0.f : kv0;
        kv1 = bad1 ? 0.f : kv1;
        const float e0 = __expf(fmaf(kv0, qc, gpk_s[t0]));
        const float e1 = __expf(fmaf(kv1, qc, gpk_s[t1]));
        d += e0 + e1;
        const float em0 = bad0 ? 0.f : e0;
        const float em1 = bad1 ? 0.f : e1;
        #pragma unroll
        for (int pp = 0; pp < 4; ++pp) {
            const unsigned wq0 = smx[pp * PGW + bb + t0];
            const unsigned wq1 = smx[pp * PGW + bb + t1];
            const float xl0 = __uint_as_float(wq0 << 16);
            const float xl1 = __uint_as_float(wq1 << 16);
            acc[2 * pp] = fmaf(em1, xl1, fmaf(em0, xl0, acc[2 * pp]));
            if (pp < 3) {
                const float xh0 = __uint_as_float(wq0 & 0xffff0000u);
                const float xh1 = __uint_as_float(wq1 & 0xffff0000u);
                acc[2 * pp + 1] = fmaf(em1, xh1, fmaf(em0, xh0, acc[2 * pp + 1]));
            }
        }
    }
    { // tap 48 singleton
        const bool s1 = (48 >= ts);
        const int bb = s1 ? B1 : B0;
        const int cc = s1 ? c1 : c0;
        const int ww = s1 ? w1 : w0;
        float kv = smk[bb + 48];
        const bool bad = (((cc + 48) & 63) < ww);
        kv = bad ? 0.f : kv;
        const float e = __expf(fmaf(kv, qc, gpk_s[48]));
        d += e;
        const float em = bad ? 0.f : e;
        #pragma unroll
        for (int pp = 0; pp < 4; ++pp) {
            const unsigned wq = smx[pp * PGW + bb + 48];
            acc[2 * pp] = fmaf(em, __uint_as_float(wq << 16), acc[2 * pp]);
            if (pp < 3)
                acc[2 * pp + 1] = fmaf(em, __uint_as_float(wq & 0xffff0000u), acc[2 * pp + 1]);
        }
    }
    // fixup: odd ts < 49 -> tap ts-1 used seg1 base; swap for seg0.
    if (ts < 49 && (ts & 1)) {
        const int tw = ts - 1;
        const float gw = gpk_s[tw];
        float kw = smk[B1 + tw];
        const bool bw = (((c1 + tw) & 63) < w1);
        kw = bw ? 0.f : kw;
        const float ew  = __expf(fmaf(kw, qc, gw));
        const float emw = bw ? 0.f : ew;
        float kr = smk[B0 + tw];
        const bool br = (((c0 + tw) & 63) < w0);
        kr = br ? 0.f : kr;
        const float er  = __expf(fmaf(kr, qc, gw));
        const float emr = br ? 0.f : er;
        d += er - ew;
        #pragma unroll
        for (int pp = 0; pp < 4; ++pp) {
            const unsigned wqw = smx[pp * PGW + B1 + tw];
            const unsigned wqr = smx[pp * PGW + B0 + tw];
            acc[2 * pp] += emr * __uint_as_float(wqr << 16)
                         - emw * __uint_as_float(wqw << 16);
            if (pp < 3)
                acc[2 * pp + 1] += emr * __uint_as_float(wqr & 0xffff0000u)
                                 - emw * __uint_as_float(wqw & 0xffff0000u);
        }
    }

    const float inv = 1.f / d;
    #pragma unroll
    for (int m = 0; m < MMM; ++m)
        preb[(size_t)(m * CGC + g) * HWSZ + lp] = f2b(acc[m] * inv);
}

extern "C" void kernel_launch(void* const* d_in, const int* in_sizes, int n_in,
                              void* d_out, int out_size, void* d_ws, size_t ws_size,
                              hipStream_t stream) {
    const float* x   = (const float*)d_in[0];
    const float* Wk  = (const float*)d_in[1];
    const float* bk  = (const float*)d_in[2];
    const float* Wq  = (const float*)d_in[3];
    const float* bq  = (const float*)d_in[4];
    const float* gw1 = (const float*)d_in[5];
    const float* gb1 = (const float*)d_in[6];
    const float* gw2 = (const float*)d_in[7];
    const float* gb2 = (const float*)d_in[8];
    const float* Wf  = (const float*)d_in[9];
    const float* bfv = (const float*)d_in[10];
    float* out = (float*)d_out;

    float* km  = (float*)d_ws;                              // 64*4096 f32
    float* qm  = km + CGC * HWSZ;                           // 64*4096 f32
    unsigned short* preb = (unsigned short*)(qm + CGC * HWSZ);  // 448*4096 bf16

    kq_mfma    <<<dim3(256),    1024, 0, stream>>>(x, Wk, bk, Wq, bq, km, qm);
    attn_kernel<<<dim3(4, CGC), 1024, 0, stream>>>(km, qm, x, gw1, gb1, gw2, gb2, preb);
    fconv_mfma <<<dim3(256),    1024, 0, stream>>>(preb, Wf, bfv, out);
}

// Round 9
// 107.195 us; speedup vs baseline: 1.4982x; 1.0029x over previous
//
#include <hip/hip_runtime.h>
#include <hip/hip_bf16.h>

// Problem constants (B=1)
#define CC   448   // channels
#define CGC  64    // key/query channels
#define MMM  7     // m groups
#define HWSZ 4096  // H*W
#define KK2  49    // K*K
#define GPH  32    // geometry-prior hidden

typedef __attribute__((ext_vector_type(8))) short   short8;   // 8 bf16 (4 VGPRs)
typedef __attribute__((ext_vector_type(4))) float   f32x4;
typedef __attribute__((ext_vector_type(4))) unsigned short us4;

__device__ __forceinline__ unsigned short f2b(float f) {
    union { __hip_bfloat16 h; unsigned short u; } cv;
    cv.h = __float2bfloat16(f);
    return cv.u;
}

// Padded kg-strides (stride == 4 mod 32, 16B-aligned) from r7.
#define KQ_AS  1032   // kq A kg-stride (shorts)
#define KQ_BS  136    // kq B kg-stride
#define FC_AS  904    // fconv A kg-stride
#define FC_BS  520    // fconv B kg-stride

// ---------------- Kernel 1: fused k+q GEMM, single-shot staging ----------
// Staging split into load-burst (16 loads in flight) then convert+write:
// collapses the pre-barrier latency from ~4 serialized chunks to ~1.
__global__ __launch_bounds__(1024, 4) void kq_mfma(
    const float* __restrict__ x,
    const float* __restrict__ Wk, const float* __restrict__ bk,
    const float* __restrict__ Wq, const float* __restrict__ bq,
    float* __restrict__ km, float* __restrict__ qm)
{
    __shared__ unsigned short As[56 * KQ_AS];  // 115584 B
    __shared__ unsigned short Bs[56 * KQ_BS];  //  15232 B
    __shared__ float         red[2048];        //   8192 B

    const int tid  = threadIdx.x;
    const int nT   = blockIdx.x * 16;
    const int lane = tid & 63;
    const int wid  = tid >> 6;
    const int l15  = lane & 15;
    const int l4   = lane >> 4;

    // ---- load burst: 14 A-f4 + 2 B-f4 all in flight ----
    float4 av[14];
    #pragma unroll
    for (int i = 0; i < 14; ++i) {
        int idx = tid + i * 1024;
        int row = idx / 112;
        int c   = idx - row * 112;
        const float* src = (row < 64) ? (Wk + (size_t)row * CC)
                                      : (Wq + (size_t)(row - 64) * CC);
        av[i] = *(const float4*)(src + c * 4);
    }
    float4 bv0, bv1;
    {
        int row = tid >> 2, c4 = tid & 3;
        bv0 = *(const float4*)(x + (size_t)row * HWSZ + nT + c4 * 4);
    }
    const bool hasB1 = (tid + 1024) < 1792;
    if (hasB1) {
        int idx = tid + 1024;
        int row = idx >> 2, c4 = idx & 3;
        bv1 = *(const float4*)(x + (size_t)row * HWSZ + nT + c4 * 4);
    }
    // ---- convert + LDS write ----
    #pragma unroll
    for (int i = 0; i < 14; ++i) {
        int idx = tid + i * 1024;
        int row = idx / 112;
        int c   = idx - row * 112;
        int kg = c >> 1, jo = (c & 1) * 4;
        float4 v = av[i];
        *(us4*)&As[kg * KQ_AS + row * 8 + jo] =
            (us4){ f2b(v.x), f2b(v.y), f2b(v.z), f2b(v.w) };
    }
    {
        int row = tid >> 2, c4 = tid & 3;
        int kg = row >> 3, j = row & 7;
        int b  = kg * KQ_BS + c4 * 32 + j;
        Bs[b]      = f2b(bv0.x);
        Bs[b + 8]  = f2b(bv0.y);
        Bs[b + 16] = f2b(bv0.z);
        Bs[b + 24] = f2b(bv0.w);
    }
    if (hasB1) {
        int idx = tid + 1024;
        int row = idx >> 2, c4 = idx & 3;
        int kg = row >> 3, j = row & 7;
        int b  = kg * KQ_BS + c4 * 32 + j;
        Bs[b]      = f2b(bv1.x);
        Bs[b + 8]  = f2b(bv1.y);
        Bs[b + 16] = f2b(bv1.z);
        Bs[b + 24] = f2b(bv1.w);
    }
    __syncthreads();

    const int mt = (wid & 7) * 16;
    const int kh = wid >> 3;
    f32x4 acc = (f32x4){0.f, 0.f, 0.f, 0.f};
    #pragma unroll
    for (int i = 0; i < 7; ++i) {
        int K4 = kh * 28 + i * 4;
        short8 fa = *(short8*)&As[(K4 + l4) * KQ_AS + (mt + l15) * 8];
        short8 fb = *(short8*)&Bs[(K4 + l4) * KQ_BS + l15 * 8];
        acc = __builtin_amdgcn_mfma_f32_16x16x32_bf16(fa, fb, acc, 0, 0, 0);
    }
    if (kh == 1)
        *(f32x4*)&red[(wid & 7) * 256 + lane * 4] = acc;
    __syncthreads();
    if (kh == 0) {
        f32x4 o = *(f32x4*)&red[(wid & 7) * 256 + lane * 4];
        const bool isK = (mt < 64);
        float*       Cd   = isK ? km : qm;
        const float* bias = isK ? bk : bq;
        const int rb = (mt & 63) + l4 * 4;
        #pragma unroll
        for (int r = 0; r < 4; ++r) {
            int row = rb + r;
            Cd[(size_t)row * HWSZ + nT + l15] = acc[r] + o[r] + bias[row];
        }
    }
}

// ---------------- Kernel 3: fconv GEMM, single-shot staging, bf16 B ------
__global__ __launch_bounds__(1024, 4) void fconv_mfma(
    const unsigned short* __restrict__ preb,
    const float* __restrict__ Wf, const float* __restrict__ bfv,
    float* __restrict__ out)
{
    __shared__ unsigned short As[56 * FC_AS];  // 101248 B
    __shared__ unsigned short Bs[56 * FC_BS];  //  58240 B

    const int tid  = threadIdx.x;
    const int bid  = blockIdx.x;          // 0..255
    const int nT   = (bid >> 2) * 64;
    const int oT   = (bid & 3) * 112;
    const int lane = tid & 63;
    const int wid  = tid >> 6;
    const int l15  = lane & 15;
    const int l4   = lane >> 4;

    // ---- load burst: 13 A-f4 (last guarded) + 7 B-us4 in flight ----
    float4 av[13];
    #pragma unroll
    for (int i = 0; i < 13; ++i) {
        int idx = tid + i * 1024;
        if (idx < 12544) {
            int row = idx / 112;
            int c   = idx - row * 112;
            av[i] = *(const float4*)(Wf + (size_t)(oT + row) * CC + c * 4);
        }
    }
    us4 bv[7];
    #pragma unroll
    for (int i = 0; i < 7; ++i) {
        int idx = tid + i * 1024;
        int row = idx >> 4, c4 = idx & 15;
        bv[i] = *(const us4*)(preb + (size_t)row * HWSZ + nT + c4 * 4);
    }
    // ---- convert + LDS write ----
    #pragma unroll
    for (int i = 0; i < 13; ++i) {
        int idx = tid + i * 1024;
        if (idx < 12544) {
            int row = idx / 112;
            int c   = idx - row * 112;
            int kg = c >> 1, jo = (c & 1) * 4;
            float4 v = av[i];
            *(us4*)&As[kg * FC_AS + row * 8 + jo] =
                (us4){ f2b(v.x), f2b(v.y), f2b(v.z), f2b(v.w) };
        }
    }
    #pragma unroll
    for (int i = 0; i < 7; ++i) {
        int idx = tid + i * 1024;
        int row = idx >> 4, c4 = idx & 15;
        int kg = row >> 3, j = row & 7;
        int b  = kg * FC_BS + c4 * 32 + j;
        Bs[b]      = bv[i].x;
        Bs[b + 8]  = bv[i].y;
        Bs[b + 16] = bv[i].z;
        Bs[b + 24] = bv[i].w;
    }
    __syncthreads();

    if (wid < 14) {
        const int mt = (wid % 7) * 16;
        const int np = wid / 7;
        f32x4 a0 = (f32x4){0.f, 0.f, 0.f, 0.f};
        f32x4 a1 = (f32x4){0.f, 0.f, 0.f, 0.f};
        #pragma unroll
        for (int i = 0; i < 14; ++i) {
            int K4 = i * 4;
            short8 fa  = *(short8*)&As[(K4 + l4) * FC_AS + (mt + l15) * 8];
            short8 fb0 = *(short8*)&Bs[(K4 + l4) * FC_BS + (np * 32 + l15) * 8];
            short8 fb1 = *(short8*)&Bs[(K4 + l4) * FC_BS + (np * 32 + 16 + l15) * 8];
            a0 = __builtin_amdgcn_mfma_f32_16x16x32_bf16(fa, fb0, a0, 0, 0, 0);
            a1 = __builtin_amdgcn_mfma_f32_16x16x32_bf16(fa, fb1, a1, 0, 0, 0);
        }
        #pragma unroll
        for (int wn2 = 0; wn2 < 2; ++wn2) {
            const f32x4 a = wn2 ? a1 : a0;
            #pragma unroll
            for (int r = 0; r < 4; ++r) {
                int row = oT + mt + l4 * 4 + r;
                int col = nT + np * 32 + wn2 * 16 + l15;
                out[(size_t)row * HWSZ + col] = a[r] + bfv[row];
            }
        }
    }
}

// ---------------- Kernel 2: attention, bf16x2-packed x pages -------------
// r8-verified math; staging restructured: 7 x-page loads issue FIRST and
// stay in flight under guard-zeroing + km + gpk + qc work, then pack+write.
#define GLO 196
#define GHI 260
#define PGW (GLO + HWSZ + GHI)   // 4552 words per page

__global__ __launch_bounds__(1024, 4) void attn_kernel(
    const float* __restrict__ km, const float* __restrict__ qm,
    const float* __restrict__ x,
    const float* __restrict__ gw1, const float* __restrict__ gb1,
    const float* __restrict__ gw2, const float* __restrict__ gb2,
    unsigned short* __restrict__ preb)
{
    __shared__ __align__(16) float        smk[PGW];        // km page (f32)
    __shared__ __align__(16) unsigned int smx[4 * PGW];    // packed x pages
    __shared__ float gpk_s[KK2];

    const int tid = threadIdx.x;
    const int g   = blockIdx.y;
    const int lp  = blockIdx.x * 1024 + tid;

    // ---- issue all 7 x-page loads first (stay in flight) ----
    float4 xra[4], xrb3[3];
    #pragma unroll
    for (int pp = 0; pp < 4; ++pp)
        xra[pp] = ((const float4*)(x + (size_t)(2 * pp * CGC + g) * HWSZ))[tid];
    #pragma unroll
    for (int pp = 0; pp < 3; ++pp)
        xrb3[pp] = ((const float4*)(x + (size_t)((2 * pp + 1) * CGC + g) * HWSZ))[tid];

    // zero guard bands: 5 pages x (49 lo + 65 hi) float4 regions
    if (tid < 5 * 114) {
        int page = tid / 114;
        int r    = tid - page * 114;
        int w    = (r < 49) ? r * 4 : (GLO + HWSZ + (r - 49) * 4);
        if (page == 0)
            *(float4*)&smk[w] = (float4){0.f, 0.f, 0.f, 0.f};
        else
            *(uint4*)&smx[(page - 1) * PGW + w] = (uint4){0u, 0u, 0u, 0u};
    }
    // stage km page (f32)
    {
        const float4* s0 = (const float4*)(km + (size_t)g * HWSZ);
        *(float4*)&smk[GLO + tid * 4] = s0[tid];
    }
    // fused geometry prior, row g (49 values)
    if (tid < KK2) {
        int di = tid / 7, dj = tid - di * 7;
        float xp = (float)(dj - 3);
        float yp = (float)(3 - di);
        float a2 = gb2[g];
        #pragma unroll
        for (int j = 0; j < GPH; ++j) {
            float h = fmaxf(gw1[j * 2 + 0] * xp + gw1[j * 2 + 1] * yp + gb1[j], 0.f);
            a2 = fmaf(gw2[g * GPH + j], h, a2);
        }
        gpk_s[tid] = a2;
    }

    // q center tap under the weird view: n = lp*49 + 24
    float qc;
    {
        int nc = lp * KK2 + 24;
        int pc = nc >> 12, lc = nc & 4095;
        int dic = (pc * 37) >> 8, djc = pc - dic * 7;
        int i = (lc >> 6) + dic - 3, j = (lc & 63) + djc - 3;
        bool ok = ((unsigned)i < 64u) && ((unsigned)j < 64u);
        qc = ok ? qm[(size_t)g * HWSZ + i * 64 + j] : 0.f;
    }

    // ---- pack + write the x pages (loads drain here, late) ----
    #pragma unroll
    for (int pp = 0; pp < 4; ++pp) {
        float4 a = xra[pp];
        float4 b = (pp < 3) ? xrb3[pp] : (float4){0.f, 0.f, 0.f, 0.f};
        uint4 w;
        w.x = ((unsigned)f2b(b.x) << 16) | f2b(a.x);
        w.y = ((unsigned)f2b(b.y) << 16) | f2b(a.y);
        w.z = ((unsigned)f2b(b.z) << 16) | f2b(a.z);
        w.w = ((unsigned)f2b(b.w) << 16) | f2b(a.w);
        *(uint4*)&smx[pp * PGW + GLO + tid * 4] = w;
    }

    // per-thread segment constants (taps span <=2 p-segments)
    const int n0 = lp * KK2;
    const int p0 = n0 >> 12;
    const int l0 = n0 & 4095;
    const int ts = ((p0 + 1) << 12) - n0;          // taps in segment 0 (>=1)
    const int di0 = (p0 * 37) >> 8, dj0 = p0 - di0 * 7;
    const int p1  = p0 + 1;
    const int di1 = (p1 * 37) >> 8, dj1 = p1 - di1 * 7;
    const int dm0 = dj0 - 3, dm1 = dj1 - 3;
    const int B0 = GLO + l0 + (di0 - 3) * 64 + dm0;
    const int B1 = GLO + l0 - HWSZ + (di1 - 3) * 64 + dm1;
    const int c0 = l0 + (dm0 > 0 ? dm0 : 0), w0 = (dm0 < 0) ? -dm0 : dm0;
    const int c1 = l0 + (dm1 > 0 ? dm1 : 0), w1 = (dm1 < 0) ? -dm1 : dm1;

    __syncthreads();   // everything staged; only barrier in the kernel

    float d = 0.f;
    float acc[MMM];
    #pragma unroll
    for (int m = 0; m < MMM; ++m) acc[m] = 0.f;

    // 24 tap-pairs, one base/mask select per pair; packed x reads
    #pragma unroll
    for (int tp = 0; tp < 24; ++tp) {
        const int t0 = 2 * tp, t1 = t0 + 1;
        const bool s1 = (t1 >= ts);
        const int bb = s1 ? B1 : B0;
        const int cc = s1 ? c1 : c0;
        const int ww = s1 ? w1 : w0;
        float kv0 = smk[bb + t0];
        float kv1 = smk[bb + t1];
        const bool bad0 = (((cc + t0) & 63) < ww);
        const bool bad1 = (((cc + t1) & 63) < ww);
        kv0 = bad0 ? 0.f : kv0;
        kv1 = bad1 ? 0.f : kv1;
        const float e0 = __expf(fmaf(kv0, qc, gpk_s[t0]));
        const float e1 = __expf(fmaf(kv1, qc, gpk_s[t1]));
        d += e0 + e1;
        const float em0 = bad0 ? 0.f : e0;
        const float em1 = bad1 ? 0.f : e1;
        #pragma unroll
        for (int pp = 0; pp < 4; ++pp) {
            const unsigned wq0 = smx[pp * PGW + bb + t0];
            const unsigned wq1 = smx[pp * PGW + bb + t1];
            const float xl0 = __uint_as_float(wq0 << 16);
            const float xl1 = __uint_as_float(wq1 << 16);
            acc[2 * pp] = fmaf(em1, xl1, fmaf(em0, xl0, acc[2 * pp]));
            if (pp < 3) {
                const float xh0 = __uint_as_float(wq0 & 0xffff0000u);
                const float xh1 = __uint_as_float(wq1 & 0xffff0000u);
                acc[2 * pp + 1] = fmaf(em1, xh1, fmaf(em0, xh0, acc[2 * pp + 1]));
            }
        }
    }
    { // tap 48 singleton
        const bool s1 = (48 >= ts);
        const int bb = s1 ? B1 : B0;
        const int cc = s1 ? c1 : c0;
        const int ww = s1 ? w1 : w0;
        float kv = smk[bb + 48];
        const bool bad = (((cc + 48) & 63) < ww);
        kv = bad ? 0.f : kv;
        const float e = __expf(fmaf(kv, qc, gpk_s[48]));
        d += e;
        const float em = bad ? 0.f : e;
        #pragma unroll
        for (int pp = 0; pp < 4; ++pp) {
            const unsigned wq = smx[pp * PGW + bb + 48];
            acc[2 * pp] = fmaf(em, __uint_as_float(wq << 16), acc[2 * pp]);
            if (pp < 3)
                acc[2 * pp + 1] = fmaf(em, __uint_as_float(wq & 0xffff0000u), acc[2 * pp + 1]);
        }
    }
    // fixup: odd ts < 49 -> tap ts-1 used seg1 base; swap for seg0.
    if (ts < 49 && (ts & 1)) {
        const int tw = ts - 1;
        const float gw = gpk_s[tw];
        float kw = smk[B1 + tw];
        const bool bw = (((c1 + tw) & 63) < w1);
        kw = bw ? 0.f : kw;
        const float ew  = __expf(fmaf(kw, qc, gw));
        const float emw = bw ? 0.f : ew;
        float kr = smk[B0 + tw];
        const bool br = (((c0 + tw) & 63) < w0);
        kr = br ? 0.f : kr;
        const float er  = __expf(fmaf(kr, qc, gw));
        const float emr = br ? 0.f : er;
        d += er - ew;
        #pragma unroll
        for (int pp = 0; pp < 4; ++pp) {
            const unsigned wqw = smx[pp * PGW + B1 + tw];
            const unsigned wqr = smx[pp * PGW + B0 + tw];
            acc[2 * pp] += emr * __uint_as_float(wqr << 16)
                         - emw * __uint_as_float(wqw << 16);
            if (pp < 3)
                acc[2 * pp + 1] += emr * __uint_as_float(wqr & 0xffff0000u)
                                 - emw * __uint_as_float(wqw & 0xffff0000u);
        }
    }

    const float inv = 1.f / d;
    #pragma unroll
    for (int m = 0; m < MMM; ++m)
        preb[(size_t)(m * CGC + g) * HWSZ + lp] = f2b(acc[m] * inv);
}

extern "C" void kernel_launch(void* const* d_in, const int* in_sizes, int n_in,
                              void* d_out, int out_size, void* d_ws, size_t ws_size,
                              hipStream_t stream) {
    const float* x   = (const float*)d_in[0];
    const float* Wk  = (const float*)d_in[1];
    const float* bk  = (const float*)d_in[2];
    const float* Wq  = (const float*)d_in[3];
    const float* bq  = (const float*)d_in[4];
    const float* gw1 = (const float*)d_in[5];
    const float* gb1 = (const float*)d_in[6];
    const float* gw2 = (const float*)d_in[7];
    const float* gb2 = (const float*)d_in[8];
    const float* Wf  = (const float*)d_in[9];
    const float* bfv = (const float*)d_in[10];
    float* out = (float*)d_out;

    float* km  = (float*)d_ws;                              // 64*4096 f32
    float* qm  = km + CGC * HWSZ;                           // 64*4096 f32
    unsigned short* preb = (unsigned short*)(qm + CGC * HWSZ);  // 448*4096 bf16

    kq_mfma    <<<dim3(256),    1024, 0, stream>>>(x, Wk, bk, Wq, bq, km, qm);
    attn_kernel<<<dim3(4, CGC), 1024, 0, stream>>>(km, qm, x, gw1, gb1, gw2, gb2, preb);
    fconv_mfma <<<dim3(256),    1024, 0, stream>>>(preb, Wf, bfv, out);
}